// Round 1
// baseline (1013.049 us; speedup 1.0000x reference)
//
#include <hip/hip_runtime.h>

// LSTM B=512 T=1024 H=150 I=1  + Linear(150->1) + sigmoid.
// 32 blocks x 512 threads. Block owns 16 sequences (N of one MFMA tile).
// M = 640 "virtual rows" = 4*cell+gate interleave (cells padded 150->160),
//   vrow 600 carries W_out (out preact rides the MFMA).
// K = 160: k<150 = h (f16, LDS double-buffered), k=150 = const 1.0 (bias col),
//   k=151 = x_t (written per step), k>=152 = zero pad.
// Weights pre-scaled by -log2e (sigmoid rows i,f,o + out row) or +2log2e (g rows)
//   so pointwise needs only exp2 + rcp (7 trans/cell).

typedef _Float16 half8 __attribute__((ext_vector_type(8)));
typedef float f32x4 __attribute__((ext_vector_type(4)));

#define LOG2E 1.44269504088896340736f
#define TWOLOG2E 2.88539008177792681472f

__global__ __launch_bounds__(512, 2) void lstm_kernel(
    const float* __restrict__ x,      // [512][1024]
    const float* __restrict__ W_ih,   // [600] (I=1)
    const float* __restrict__ W_hh,   // [600][150]
    const float* __restrict__ b_ih,   // [600]
    const float* __restrict__ b_hh,   // [600]
    const float* __restrict__ W_out,  // [150]
    const float* __restrict__ b_out,  // [1]
    float* __restrict__ out)          // [512][1024]
{
  const int tid  = threadIdx.x;
  const int wid  = tid >> 6;
  const int lane = tid & 63;
  const int q    = lane >> 4;   // k-quad for fragments; cell offset within tile for D
  const int b    = lane & 15;   // batch col (B n / D col); A row m for weight frags
  const int bid  = blockIdx.x;

  // stride 168 f16 = 336 B: b128 reads land ~2-way on banks (free)
  __shared__ __align__(16) _Float16 hbuf[2][16][168];
  __shared__ _Float16 xlds[16][1024];

  // ---- prologue: zero hbuf, stage x as f16 ----
  for (int i = tid; i < 2*16*168; i += 512)
    (&hbuf[0][0][0])[i] = (_Float16)0.0f;
  {
    const float4* x4 = (const float4*)(x + (size_t)bid * 16 * 1024);
    for (int i = tid; i < 16*256; i += 512) {
      int row = i >> 8, c4 = i & 255;
      float4 v = x4[row*256 + c4];
      xlds[row][c4*4+0] = (_Float16)v.x;
      xlds[row][c4*4+1] = (_Float16)v.y;
      xlds[row][c4*4+2] = (_Float16)v.z;
      xlds[row][c4*4+3] = (_Float16)v.w;
    }
  }
  __syncthreads();
  if (tid < 32) hbuf[tid>>4][tid&15][150] = (_Float16)1.0f;  // bias column
  if (tid < 16) hbuf[0][tid][151] = xlds[tid][0];            // x_0
  __syncthreads();

  // ---- weight fragments (A operand), 25 frags = 100 VGPR/lane ----
  const float bo = b_out[0];
  half8 wf[5][5];
#pragma unroll
  for (int tl = 0; tl < 5; ++tl) {
    const int tg   = wid*5 + tl;
    const int vrow = tg*16 + b;       // A: m = lane&15
    const int cell = vrow >> 2, gate = vrow & 3;
    const float alpha = (gate == 2) ? TWOLOG2E : -LOG2E;
#pragma unroll
    for (int s = 0; s < 5; ++s) {
      half8 v;
#pragma unroll
      for (int j = 0; j < 8; ++j) {
        const int k = s*32 + q*8 + j; // same (q,j)->k map as B frags: pairing-consistent
        float w = 0.0f;
        if (vrow == 600) {            // out row
          if (k < 150)       w = -LOG2E * W_out[k];
          else if (k == 150) w = -LOG2E * bo;
        } else if (cell < 150) {
          const int orow = gate*150 + cell;
          if (k < 150)       w = alpha * W_hh[orow*150 + k];
          else if (k == 150) w = alpha * (b_ih[orow] + b_hh[orow]);
          else if (k == 151) w = alpha * W_ih[orow];
        }
        v[j] = (_Float16)w;
      }
      wf[tl][s] = v;
    }
  }

  float cst[5] = {0.f, 0.f, 0.f, 0.f, 0.f};      // per-lane c state (one per owned tile)
  const bool is_x   = (wid == 7) && (q == 3);    // cell 151 lanes
  const bool is_out = (wid == 7) && (q == 2);    // vrow 600 -> tile 37, m=8 -> quad2 reg0
  float* outp = out + ((size_t)bid*16 + b) * 1024;

  int cur = 0;
  for (int t = 0; t <= 1024; ++t) {
    _Float16 xv = (_Float16)0.0f;
    if (is_x && t < 1023) xv = xlds[b][t+1];     // issued early, used after pointwise

    half8 bf[5];
#pragma unroll
    for (int s = 0; s < 5; ++s)
      bf[s] = *(const half8*)&hbuf[cur][b][s*32 + q*8];

    f32x4 acc[5];
#pragma unroll
    for (int tl = 0; tl < 5; ++tl) {
      f32x4 a = {0.f, 0.f, 0.f, 0.f};
#pragma unroll
      for (int s = 0; s < 5; ++s)
        a = __builtin_amdgcn_mfma_f32_16x16x32_f16(wf[tl][s], bf[s], a, 0, 0, 0);
      acc[tl] = a;
    }

    // out_t-1 = sigmoid(Wout.h_{t-1}+b_out); acc already scaled by -log2e
    if (is_out && t >= 1)
      outp[t-1] = __builtin_amdgcn_rcpf(1.0f + __builtin_amdgcn_exp2f(acc[2][0]));
    if (t == 1024) break;

    const int nxt = cur ^ 1;
#pragma unroll
    for (int tl = 0; tl < 5; ++tl) {
      const int cellg = (wid*5 + tl)*4 + q;
      // acc regs: 0=i',1=f',2=g',3=o' (pre-scaled preacts)
      const float ei = __builtin_amdgcn_exp2f(acc[tl][0]);
      const float ef = __builtin_amdgcn_exp2f(acc[tl][1]);
      const float eg = __builtin_amdgcn_exp2f(acc[tl][2]);
      const float eo = __builtin_amdgcn_exp2f(acc[tl][3]);
      const float A  = 1.0f + ei;     // 1/i
      const float F  = 1.0f + ef;     // 1/f
      const float G1 = eg + 1.0f;
      const float Gm = eg - 1.0f;     // g = Gm/G1
      const float AG = A * G1;
      const float num = fmaf(cst[tl], AG, Gm * F);       // c*A*G1 + Gm*F
      const float cn  = num * __builtin_amdgcn_rcpf(F * AG);
      cst[tl] = cn;
      const float ec = __builtin_amdgcn_exp2f(TWOLOG2E * cn);
      const float h  = (ec - 1.0f) *
                       __builtin_amdgcn_rcpf((1.0f + eo) * (ec + 1.0f)); // o*tanh(c)
      if (cellg < 150) hbuf[nxt][b][cellg] = (_Float16)h;
    }
    if (is_x && t < 1023) hbuf[nxt][b][151] = xv;  // x_{t+1}
    __syncthreads();
    cur = nxt;
  }
}

extern "C" void kernel_launch(void* const* d_in, const int* in_sizes, int n_in,
                              void* d_out, int out_size, void* d_ws, size_t ws_size,
                              hipStream_t stream) {
  const float* x     = (const float*)d_in[0];
  const float* W_ih  = (const float*)d_in[1];
  const float* W_hh  = (const float*)d_in[2];
  const float* b_ih  = (const float*)d_in[3];
  const float* b_hh  = (const float*)d_in[4];
  const float* W_out = (const float*)d_in[5];
  const float* b_out = (const float*)d_in[6];
  lstm_kernel<<<dim3(32), dim3(512), 0, stream>>>(
      x, W_ih, W_hh, b_ih, b_hh, W_out, b_out, (float*)d_out);
}